// Round 20
// baseline (98.767 us; speedup 1.0000x reference)
//
#include <hip/hip_runtime.h>
#include <math.h>

// Problem constants (reference: N=32, K=16, BINS=100, DIM=2, sample_size=100)
#define NBINS 100
#define NN    32
#define KD    16
#define NT    99    // sample_size-1

// ws float offsets
#define OFF_H   0        // h[p][j][d] 100*16*2 = 3200
#define OFF_QT  3200     // qt[j][n] = Q[n][j]  16*32 = 512
#define OFF_XL  3712     // x_last 64

// ---------------- f32 cross-lane primitives (VALU-only) --------------------
template<int CTRL>
__device__ __forceinline__ float fmov_dpp(float x) {
  return __int_as_float(
      __builtin_amdgcn_update_dpp(0, __float_as_int(x), CTRL, 0xf, 0xf, true));
}
__device__ __forceinline__ float frdlane(float x, int lane) {
  return __int_as_float(__builtin_amdgcn_readlane(__float_as_int(x), lane));
}
// whole-wave shift-up-by-1: out[l] = in[l-1], out[0] = c0  (row_shr:1 + fixups)
__device__ __forceinline__ float fshup(float x, float c0, int lane) {
  float v = fmov_dpp<0x111>(x);
  float x15 = frdlane(x, 15), x31 = frdlane(x, 31), x47 = frdlane(x, 47);
  v = (lane == 0)  ? c0  : v;
  v = (lane == 16) ? x15 : v;
  v = (lane == 32) ? x31 : v;
  v = (lane == 48) ? x47 : v;
  return v;
}
// element k (0..99) from (lo,hi) register pair; k wave-uniform
__device__ __forceinline__ float frdpos(float lo, float hi, int k) {
  return (k < 64) ? frdlane(lo, k) : frdlane(hi, k - 64);
}
// fast f32 reciprocal: HW rcp + 1 Newton step (~1 ulp)
__device__ __forceinline__ float frcp(float x) {
  float r = __builtin_amdgcn_rcpf(x);
  return r * (2.0f - x * r);
}

// readlane flavors for the forward-Schur loop split
#define RD_LO(lo, hi, idx)  frdlane(lo, idx)
#define RD_MIX(lo, hi, idx) frdpos(lo, hi, ((idx) <= 99 ? (idx) : 99))

// one forward-Schur step (scalar-lookahead form, verified round 11)
#define FWD_STEP(RD)                                                     \
  {                                                                      \
    float iuk = frcp(uk);                                                \
    Lrow[l * 101 + k] = u_lo * iuk;                                      \
    if (hiv) Lrow[ahi * 101 + k] = u_hi * iuk;                           \
    float dk = P * iuk * iuk;                                            \
    sdl = (l == k)   ? dk : sdl;                                         \
    sdh = (ahi == k) ? dk : sdh;                                         \
    float a0 = r0k * iuk, a1 = r1k * iuk;                                \
    float r0k1 = RD(r0_lo, r0_hi, k + 1);                                \
    float r1k1 = RD(r1_lo, r1_hi, k + 1);                                \
    float uk2  = RD(u_lo, u_hi, k + 2);                                  \
    float vk3  = RD(v_lo, v_hi, k + 3);                                  \
    if (l > k)   { r0_lo -= a0 * u_lo; r1_lo -= a1 * u_lo; }             \
    if (ahi > k) { r0_hi -= a0 * u_hi; r1_hi -= a1 * u_hi; }             \
    r0k = r0k1 - a0 * uk1;                                               \
    r1k = r1k1 - a1 * uk1;                                               \
    float g = vk1 * iuk;                                                 \
    float u63 = frdlane(u_lo, 63);                                       \
    float u1_lo = fshup(u_lo, 0.0f, l);                                  \
    float u1_hi = fshup(u_hi, u63, l);                                   \
    u_lo = u1_lo - g * v_lo;  u_hi = u1_hi - g * v_hi;                   \
    v_lo = v_lo - g * u1_lo;  v_hi = v_hi - g * u1_hi;                   \
    P *= (1.0f - g * g);                                                 \
    float uk_n  = uk  - g * vk1;                                         \
    float uk1_n = uk1 - g * vk2;                                         \
    float vk1_n = vk2 - g * uk1;                                         \
    float vk2_n = vk3 - g * uk2;                                         \
    uk = uk_n; uk1 = uk1_n; vk1 = vk1_n; vk2 = vk2_n;                    \
  }

// ================= K1: eig (redundant per block) + Toeplitz solve ==========
// 16 blocks x 128 threads (2 waves). Wave 1 stages vT + x_last while wave 0
// runs CqS/G/Jacobi (r15-proven LDS cs-table form, 4 SWEEPS — 3 sweeps FAILS
// r14: absmax 2.125; shfl-broadcast FAILS PERF r16; full fusion FAILS PERF
// r18). ONE __syncthreads; solve is wave-0-only (single-wave lockstep).
// Backward solve: 2x unrolled, 2-row prefetch (covers ~120cy LDS latency).
__global__ __launch_bounds__(128) void k1_all(
    const float* __restrict__ x0, const float* __restrict__ v_in,
    const float* __restrict__ sigma_in, const float* __restrict__ ls_in,
    const float* __restrict__ Cq, float* __restrict__ ws)
{
  extern __shared__ float fsm[];
  float* Lrow  = fsm;                          // 100*101 = 10100
  float* vT    = Lrow + 100 * 101;             // 64*101 = 6464
  float* QTl   = vT + 64 * 101;                // 512
  __shared__ float A[16 * 17], Vv[16 * 17];
  __shared__ float csC[16], csS[16];
  __shared__ float CqS[NN * KD];

  const int tid = threadIdx.x;
  const int l = tid & 63;                      // lane within wave
  const int wv = tid >> 6;                     // wave id (0 or 1)
  const int j = blockIdx.x;
  const int r = l >> 2, c0 = l & 3;
  const float ls = ls_in[0];
  const float i2 = -0.5f / (ls * ls);
  float sig = fmaxf(sigma_in[0], 0.05f);       // clip(sigma, 5/BINS)
  const double sinvd = 1.0 / ((double)sig * (double)sig);
  const float sinvf = (float)sinvd;
  const int ahi = 64 + l;
  const bool hiv = (ahi < 100);

  float c = 0.0f;                              // c_j (wave 0 sets pre-barrier)

  if (wv == 1) {
    // ---- wave 1: stage vT (transposed) + x_last, overlapped with eig ----
    for (int p = 0; p < NBINS; ++p) vT[l * 101 + p] = v_in[p * 64 + l];
    if (j == 0) {
      float acc = 0.f;
      for (int p = 0; p < NBINS; ++p) acc += vT[l * 101 + p];
      ws[OFF_XL + l] = x0[l] + 0.01f * acc;
    }
  } else {
    // ---- wave 0: CqS, G = Cq^T Cq, V = I ----
    for (int e = l; e < NN * KD; e += 64) CqS[e] = Cq[e];
    #pragma unroll
    for (int k = 0; k < 4; ++k) {
      int ci = c0 + 4 * k;
      float acc = 0.f;
      for (int n = 0; n < NN; ++n)
        acc += CqS[n * 16 + r] * CqS[n * 16 + ci];
      A[r * 17 + ci] = acc;
      Vv[r * 17 + ci] = (r == ci) ? 1.0f : 0.0f;
    }

    // ---- Jacobi (r15 LDS-table form, f32, 4 sweeps x 15 masks, no bar) ----
    for (int sweep = 0; sweep < 4; ++sweep)
    for (int m = 1; m <= 15; ++m) {
      const int hb = 31 - __clz(m);
      const int lowm = (1 << hb) - 1;
      if (l < 8) {                             // (c,s) per pair
        int p = ((l & ~lowm) << 1) | (l & lowm), q = p ^ m;
        float app = A[p * 17 + p], aqq = A[q * 17 + q], apq = A[p * 17 + q];
        float cc = 1.0f, ss = 0.0f;
        if (fabsf(apq) > 1e-30f) {
          float th = (aqq - app) * 0.5f * __builtin_amdgcn_rcpf(apq);
          float t_ = __builtin_amdgcn_rcpf(fabsf(th) + sqrtf(th * th + 1.0f));
          t_ = (th >= 0.0f) ? t_ : -t_;
          cc = __builtin_amdgcn_rsqf(t_ * t_ + 1.0f);
          ss = t_ * cc;
        }
        csC[p] = cc; csS[p] = -ss;
        csC[q] = cc; csS[q] = ss;
      }
      const int rh = r ^ m;
      float ar = csC[r], br = csS[r];          // ordered after writes (waitcnt)
      float nA[4], nV[4];
      #pragma unroll
      for (int k = 0; k < 4; ++k) {            // batched reads (before writes)
        int ci = c0 + 4 * k, ch = ci ^ m;
        float ac = csC[ci], bc = csS[ci];
        float a_rc = A[r * 17 + ci],  a_hc = A[rh * 17 + ci];
        float a_rh = A[r * 17 + ch],  a_hh = A[rh * 17 + ch];
        float v_rc = Vv[r * 17 + ci], v_rh = Vv[r * 17 + ch];
        nA[k] = ac * (ar * a_rc + br * a_hc) + bc * (ar * a_rh + br * a_hh);
        nV[k] = ac * v_rc + bc * v_rh;
      }
      #pragma unroll
      for (int k = 0; k < 4; ++k) {            // writes (lockstep: after reads)
        int ci = c0 + 4 * k;
        A[r * 17 + ci] = nA[k];
        Vv[r * 17 + ci] = nV[k];
      }
    }

    // ---- c_j (broadcast); Q: own column only (block 0: full + publish) ----
    float muj = A[j * 17 + j];
    if (muj < 0.f) muj = 0.f;
    c = (float)(sinvd * (double)muj);
    if (j == 0) {
      for (int e = l; e < 512; e += 64) {      // QT[jq][n] = (C*U)[n][jq]
        int jq = e >> 5, n = e & 31;
        float acc = 0.f;
        for (int k2 = 0; k2 < 16; ++k2)
          acc += CqS[n * 16 + k2] * Vv[k2 * 17 + jq];
        QTl[e] = acc;
        ws[OFF_QT + e] = acc;
      }
    } else if (l < 32) {                       // only Q[:,j] needed locally
      float acc = 0.f;
      for (int k2 = 0; k2 < 16; ++k2)
        acc += CqS[l * 16 + k2] * Vv[k2 * 17 + j];
      QTl[j * 32 + l] = acc;
    }
  }

  __syncthreads();                             // vT (wave 1) / QTl (wave 0)
  if (wv == 1) return;                         // wave 1 done

  // ---- s-projection: s[d][p] at p=l (lo) / p=64+l (hi) ----
  float s0l = 0.f, s1l = 0.f, s0h = 0.f, s1h = 0.f;
  for (int n = 0; n < NN; ++n) {
    float qv = QTl[j * 32 + n];                // broadcast
    s0l += qv * vT[(2 * n) * 101 + l];
    s1l += qv * vT[(2 * n + 1) * 101 + l];
    if (hiv) {
      s0h += qv * vT[(2 * n) * 101 + ahi];
      s1h += qv * vT[(2 * n + 1) * 101 + ahi];
    }
  }

  // ---- normalized Toeplitz: t_k = c*g_k/m0 ; b = s/m0 ----
  const float m0  = 1.0f + c * (1.0f + 1e-5f);
  const float im0 = frcp(m0);
  float gl = expf((0.01f * (float)l) * (0.01f * (float)l) * i2);
  float gh = expf((0.01f * (float)ahi) * (0.01f * (float)ahi) * i2);
  float u_lo = (l == 0) ? 1.0f : c * gl * im0;
  float u_hi = hiv ? c * gh * im0 : 0.0f;
  float v_lo = (l == 0) ? 0.0f : u_lo;          // v = (0, t1, ..)
  float v_hi = u_hi;
  float r0_lo = s0l * im0, r1_lo = s1l * im0;
  float r0_hi = hiv ? s0h * im0 : 0.0f;
  float r1_hi = hiv ? s1h * im0 : 0.0f;
  float P = 1.0f;
  float sdl = 0.f, sdh = 0.f;                   // register 1/d capture

  // ---- forward Schur: scalar lookahead, split loops ----
  float uk  = frdlane(u_lo, 0);
  float uk1 = frdlane(u_lo, 1);
  float vk1 = frdlane(v_lo, 1);
  float vk2 = frdlane(v_lo, 2);
  float r0k = frdlane(r0_lo, 0);
  float r1k = frdlane(r1_lo, 0);

  for (int k = 0; k < 60; ++k)  FWD_STEP(RD_LO)    // k+3 <= 62: lo-only reads
  for (int k = 60; k < 99; ++k) FWD_STEP(RD_MIX)   // mixed, clamped
  {                                                // k = 99 peeled
    const int k = 99;
    float iuk = frcp(uk);
    Lrow[l * 101 + k] = u_lo * iuk;
    if (hiv) Lrow[ahi * 101 + k] = u_hi * iuk;
    float dk = P * iuk * iuk;
    sdh = (ahi == k) ? dk : sdh;                   // l==99 impossible
  }

  // ---- diagonal scale: w = y / d (register sd) ----
  float x0_lo = r0_lo * sdl, x1_lo = r1_lo * sdl;
  float x0_hi = r0_hi * sdh, x1_hi = r1_hi * sdh;

  // ---- backward: L~^T x = w; 2x unrolled, 2-row prefetch ----
  // Invariant at loop top: Ll/Lh hold row k.
  float Ll = Lrow[99 * 101 + l];
  float Lh = hiv ? Lrow[99 * 101 + ahi] : 0.0f;
  int k = 99;
  for (; k >= 3; k -= 2) {
    // prefetch rows k-1 and k-2 (latency covered by the two update steps)
    float rAl = Lrow[(k - 1) * 101 + l];
    float rAh = hiv ? Lrow[(k - 1) * 101 + ahi] : 0.0f;
    float rBl = Lrow[(k - 2) * 101 + l];
    float rBh = hiv ? Lrow[(k - 2) * 101 + ahi] : 0.0f;
    // step k (uses Ll = row k)
    float xk0 = frdpos(x0_lo, x0_hi, k);
    float xk1 = frdpos(x1_lo, x1_hi, k);
    if (l < k)   { x0_lo -= xk0 * Ll; x1_lo -= xk1 * Ll; }
    if (ahi < k) { x0_hi -= xk0 * Lh; x1_hi -= xk1 * Lh; }
    // step k-1 (uses row k-1; x read AFTER step-k update — sequential order)
    float yk0 = frdpos(x0_lo, x0_hi, k - 1);
    float yk1 = frdpos(x1_lo, x1_hi, k - 1);
    if (l < k - 1)   { x0_lo -= yk0 * rAl; x1_lo -= yk1 * rAl; }
    if (ahi < k - 1) { x0_hi -= yk0 * rAh; x1_hi -= yk1 * rAh; }
    Ll = rBl; Lh = rBh;
  }
  for (; k >= 1; --k) {                        // remaining steps (k=2?,1)
    float nLl = (k >= 2) ? Lrow[(k - 1) * 101 + l] : 0.0f;
    float nLh = (hiv && k >= 2) ? Lrow[(k - 1) * 101 + ahi] : 0.0f;
    float xk0 = frdpos(x0_lo, x0_hi, k);
    float xk1 = frdpos(x1_lo, x1_hi, k);
    if (l < k)   { x0_lo -= xk0 * Ll; x1_lo -= xk1 * Ll; }
    if (ahi < k) { x0_hi -= xk0 * Lh; x1_hi -= xk1 * Lh; }
    Ll = nLl; Lh = nLh;
  }

  // ---- h[p][j][d] = sinv * x[p] ----
  ws[OFF_H + l * 32 + j * 2 + 0] = sinvf * x0_lo;
  ws[OFF_H + l * 32 + j * 2 + 1] = sinvf * x1_lo;
  if (hiv) {
    ws[OFF_H + ahi * 32 + j * 2 + 0] = sinvf * x0_hi;
    ws[OFF_H + ahi * 32 + j * 2 + 1] = sinvf * x1_hi;
  }
}

// =============================== K_TAIL ====================================
// 16 blocks x 256 (4 waves -> barriers REQUIRED here). float2 everywhere.
#define L_H   0        // 3200
#define L_QT  3200     // 512
#define L_XL  3712     // 64
#define L_BC  3776     // 99*100 = 9900
#define L_Z   13676    // 99*32  = 3168
#define L_XT  16844    // 99*64  = 6336
#define L_PS  23180    // 4*64   = 256
#define L_TOT 23436

__global__ __launch_bounds__(256) void k_tail(
    const float* __restrict__ ls_in, const float* __restrict__ beta,
    const float* __restrict__ ws, float* __restrict__ out)
{
  extern __shared__ float lds[];
  const int tid = threadIdx.x;
  const float ls = ls_in[0];
  const float i2 = -0.5f / (ls * ls);

  // staging: float2 (H: 1600 pairs, QT: 256 pairs, XL: 32 pairs)
  for (int e = tid; e < 1600; e += 256)
    *(float2*)&lds[L_H + 2 * e] = *(const float2*)&ws[OFF_H + 2 * e];
  for (int e = tid; e < 256; e += 256)
    *(float2*)&lds[L_QT + 2 * e] = *(const float2*)&ws[OFF_QT + 2 * e];
  if (tid < 32)
    *(float2*)&lds[L_XL + 2 * tid] = *(const float2*)&ws[OFF_XL + 2 * tid];
  for (int e = tid; e < NT * NBINS; e += 256) {
    int t = e / NBINS, p = e - t * NBINS;
    float tst = 1.0f + (float)t * (1.0f / 99.0f);
    float dd = tst - ((float)p + 0.5f) * 0.01f;
    lds[L_BC + e] = expf(dd * dd * i2);
  }
  __syncthreads();

  // z[t][jd2:jd2+2] = sum_p Bc[t][p] * h[p][jd2:jd2+2]   (float2 h reads)
  for (int dot = tid; dot < NT * 16; dot += 256) {
    int t = dot >> 4, jd2 = (dot & 15) << 1;
    float ax = 0.f, ay = 0.f;
    for (int p = 0; p < NBINS; ++p) {
      float b = lds[L_BC + t * NBINS + p];
      float2 h2 = *(const float2*)&lds[L_H + p * 32 + jd2];
      ax += b * h2.x; ay += b * h2.y;
    }
    *(float2*)&lds[L_Z + t * 32 + jd2] = make_float2(ax, ay);
  }
  __syncthreads();

  // xt[t][n][0:2] = xl[n] + trel * sum_j qt[j][n] * z[t][2j:2j+2]
  for (int e = tid; e < NT * 32; e += 256) {
    int t = e >> 5, n = e & 31;
    float ax = 0.f, ay = 0.f;
    for (int jq = 0; jq < 16; ++jq) {
      float q = lds[L_QT + jq * 32 + n];
      float2 z2 = *(const float2*)&lds[L_Z + t * 32 + jq * 2];
      ax += q * z2.x; ay += q * z2.y;
    }
    float trel = (float)t * (1.0f / 99.0f);
    float2 xl = *(const float2*)&lds[L_XL + 2 * n];
    *(float2*)&lds[L_XT + t * 64 + 2 * n] =
        make_float2(xl.x + trel * ax, xl.y + trel * ay);
  }
  __syncthreads();

  // intensity: 64 pairs per block, 4-way t-split
  {
    const int pl = tid & 63, tc = tid >> 6;
    const int gp = blockIdx.x * 64 + pl;
    const int i = gp >> 5, jj = gp & 31;
    const float bsum = beta[i] + beta[jj];
    const int t0 = tc * 25, t1 = (t0 + 25 < NT) ? t0 + 25 : NT;
    float acc = 0.f;
    for (int t = t0; t < t1; ++t) {
      float2 xi = *(const float2*)&lds[L_XT + t * 64 + 2 * i];
      float2 xj = *(const float2*)&lds[L_XT + t * 64 + 2 * jj];
      float dx = xi.x - xj.x, dy = xi.y - xj.y;
      float sq = fmaxf(dx * dx + dy * dy, 1e-12f);
      acc += expf(bsum - sqrtf(sq));
    }
    lds[L_PS + tc * 64 + pl] = acc;
  }
  __syncthreads();
  if (tid < 64) {
    float s = lds[L_PS + tid] + lds[L_PS + 64 + tid]
            + lds[L_PS + 128 + tid] + lds[L_PS + 192 + tid];
    out[blockIdx.x * 64 + tid] = s * (1.0f / 99.0f);
  }
}

extern "C" void kernel_launch(void* const* d_in, const int* in_sizes, int n_in,
                              void* d_out, int out_size, void* d_ws, size_t ws_size,
                              hipStream_t stream) {
  const float* x0    = (const float*)d_in[0];
  const float* v     = (const float*)d_in[1];
  const float* beta  = (const float*)d_in[2];
  const float* sigma = (const float*)d_in[3];
  // d_in[4] = x0c: unused (B_cross row 0 is zero)
  const float* ls    = (const float*)d_in[5];
  const float* Cq    = (const float*)d_in[6];
  float* out = (float*)d_out;
  float* ws  = (float*)d_ws;

  const size_t smem1 = (size_t)(100 * 101 + 64 * 101 + 512) * sizeof(float); // ~66.7 KB
  k1_all<<<16, 128, smem1, stream>>>(x0, v, sigma, ls, Cq, ws);
  k_tail<<<16, 256, (size_t)L_TOT * sizeof(float), stream>>>(ls, beta, ws, out);
}

// Round 21
// 84.945 us; speedup vs baseline: 1.1627x; 1.1627x over previous
//
#include <hip/hip_runtime.h>
#include <math.h>

// Problem constants (reference: N=32, K=16, BINS=100, DIM=2, sample_size=100)
#define NBINS 100
#define NN    32
#define KD    16
#define NT    99    // sample_size-1

// ws float offsets
#define OFF_H   0        // h[p][j][d] 100*16*2 = 3200
#define OFF_QT  3200     // qt[j][n] = Q[n][j]  16*32 = 512
#define OFF_XL  3712     // x_last 64

// ---------------- f32 cross-lane primitives (VALU-only) --------------------
template<int CTRL>
__device__ __forceinline__ float fmov_dpp(float x) {
  return __int_as_float(
      __builtin_amdgcn_update_dpp(0, __float_as_int(x), CTRL, 0xf, 0xf, true));
}
__device__ __forceinline__ float frdlane(float x, int lane) {
  return __int_as_float(__builtin_amdgcn_readlane(__float_as_int(x), lane));
}
// whole-wave shift-up-by-1: out[l] = in[l-1], out[0] = c0  (row_shr:1 + fixups)
__device__ __forceinline__ float fshup(float x, float c0, int lane) {
  float v = fmov_dpp<0x111>(x);
  float x15 = frdlane(x, 15), x31 = frdlane(x, 31), x47 = frdlane(x, 47);
  v = (lane == 0)  ? c0  : v;
  v = (lane == 16) ? x15 : v;
  v = (lane == 32) ? x31 : v;
  v = (lane == 48) ? x47 : v;
  return v;
}
// element k (0..99) from (lo,hi) register pair; k wave-uniform
__device__ __forceinline__ float frdpos(float lo, float hi, int k) {
  return (k < 64) ? frdlane(lo, k) : frdlane(hi, k - 64);
}
// fast f32 reciprocal: HW rcp + 1 Newton step (~1 ulp)
__device__ __forceinline__ float frcp(float x) {
  float r = __builtin_amdgcn_rcpf(x);
  return r * (2.0f - x * r);
}

// readlane flavors for the forward-Schur loop split
#define RD_LO(lo, hi, idx)  frdlane(lo, idx)
#define RD_MIX(lo, hi, idx) frdpos(lo, hi, ((idx) <= 99 ? (idx) : 99))

// one forward-Schur step (scalar-lookahead form, verified round 11)
#define FWD_STEP(RD)                                                     \
  {                                                                      \
    float iuk = frcp(uk);                                                \
    Lrow[l * 101 + k] = u_lo * iuk;                                      \
    if (hiv) Lrow[ahi * 101 + k] = u_hi * iuk;                           \
    float dk = P * iuk * iuk;                                            \
    sdl = (l == k)   ? dk : sdl;                                         \
    sdh = (ahi == k) ? dk : sdh;                                         \
    float a0 = r0k * iuk, a1 = r1k * iuk;                                \
    float r0k1 = RD(r0_lo, r0_hi, k + 1);                                \
    float r1k1 = RD(r1_lo, r1_hi, k + 1);                                \
    float uk2  = RD(u_lo, u_hi, k + 2);                                  \
    float vk3  = RD(v_lo, v_hi, k + 3);                                  \
    if (l > k)   { r0_lo -= a0 * u_lo; r1_lo -= a1 * u_lo; }             \
    if (ahi > k) { r0_hi -= a0 * u_hi; r1_hi -= a1 * u_hi; }             \
    r0k = r0k1 - a0 * uk1;                                               \
    r1k = r1k1 - a1 * uk1;                                               \
    float g = vk1 * iuk;                                                 \
    float u63 = frdlane(u_lo, 63);                                       \
    float u1_lo = fshup(u_lo, 0.0f, l);                                  \
    float u1_hi = fshup(u_hi, u63, l);                                   \
    u_lo = u1_lo - g * v_lo;  u_hi = u1_hi - g * v_hi;                   \
    v_lo = v_lo - g * u1_lo;  v_hi = v_hi - g * u1_hi;                   \
    P *= (1.0f - g * g);                                                 \
    float uk_n  = uk  - g * vk1;                                         \
    float uk1_n = uk1 - g * vk2;                                         \
    float vk1_n = vk2 - g * uk1;                                         \
    float vk2_n = vk3 - g * uk2;                                         \
    uk = uk_n; uk1 = uk1_n; vk1 = vk1_n; vk2 = vk2_n;                    \
  }

// ================= K1: eig (redundant per block) + Toeplitz solve ==========
// 16 blocks x 128 threads (2 waves). Wave 1 stages vT + x_last while wave 0
// runs CqS/G/Jacobi (r15-proven LDS cs-table form, 4 SWEEPS — 3 sweeps FAILS
// r14: absmax 2.125; shfl-broadcast FAILS PERF r16; full fusion FAILS PERF
// r18; bwd 2x-unroll NEUTRAL r20). ONE __syncthreads; solve is wave-0-only.
__global__ __launch_bounds__(128) void k1_all(
    const float* __restrict__ x0, const float* __restrict__ v_in,
    const float* __restrict__ sigma_in, const float* __restrict__ ls_in,
    const float* __restrict__ Cq, float* __restrict__ ws)
{
  extern __shared__ float fsm[];
  float* Lrow  = fsm;                          // 100*101 = 10100
  float* vT    = Lrow + 100 * 101;             // 64*101 = 6464
  float* QTl   = vT + 64 * 101;                // 512
  __shared__ float A[16 * 17], Vv[16 * 17];
  __shared__ float csC[16], csS[16];
  __shared__ float CqS[NN * KD];

  const int tid = threadIdx.x;
  const int l = tid & 63;                      // lane within wave
  const int wv = tid >> 6;                     // wave id (0 or 1)
  const int j = blockIdx.x;
  const int r = l >> 2, c0 = l & 3;
  const float ls = ls_in[0];
  const float i2 = -0.5f / (ls * ls);
  float sig = fmaxf(sigma_in[0], 0.05f);       // clip(sigma, 5/BINS)
  const double sinvd = 1.0 / ((double)sig * (double)sig);
  const float sinvf = (float)sinvd;
  const int ahi = 64 + l;
  const bool hiv = (ahi < 100);

  float c = 0.0f;                              // c_j (wave 0 sets pre-barrier)

  if (wv == 1) {
    // ---- wave 1: stage vT (transposed) + x_last, overlapped with eig ----
    for (int p = 0; p < NBINS; ++p) vT[l * 101 + p] = v_in[p * 64 + l];
    if (j == 0) {
      float acc = 0.f;
      for (int p = 0; p < NBINS; ++p) acc += vT[l * 101 + p];
      ws[OFF_XL + l] = x0[l] + 0.01f * acc;
    }
  } else {
    // ---- wave 0: CqS, G = Cq^T Cq, V = I ----
    for (int e = l; e < NN * KD; e += 64) CqS[e] = Cq[e];
    #pragma unroll
    for (int k = 0; k < 4; ++k) {
      int ci = c0 + 4 * k;
      float acc = 0.f;
      for (int n = 0; n < NN; ++n)
        acc += CqS[n * 16 + r] * CqS[n * 16 + ci];
      A[r * 17 + ci] = acc;
      Vv[r * 17 + ci] = (r == ci) ? 1.0f : 0.0f;
    }

    // ---- Jacobi (r15 LDS-table form, f32, 4 sweeps x 15 masks, no bar) ----
    for (int sweep = 0; sweep < 4; ++sweep)
    for (int m = 1; m <= 15; ++m) {
      const int hb = 31 - __clz(m);
      const int lowm = (1 << hb) - 1;
      if (l < 8) {                             // (c,s) per pair
        int p = ((l & ~lowm) << 1) | (l & lowm), q = p ^ m;
        float app = A[p * 17 + p], aqq = A[q * 17 + q], apq = A[p * 17 + q];
        float cc = 1.0f, ss = 0.0f;
        if (fabsf(apq) > 1e-30f) {
          float th = (aqq - app) * 0.5f * __builtin_amdgcn_rcpf(apq);
          float t_ = __builtin_amdgcn_rcpf(fabsf(th) + sqrtf(th * th + 1.0f));
          t_ = (th >= 0.0f) ? t_ : -t_;
          cc = __builtin_amdgcn_rsqf(t_ * t_ + 1.0f);
          ss = t_ * cc;
        }
        csC[p] = cc; csS[p] = -ss;
        csC[q] = cc; csS[q] = ss;
      }
      const int rh = r ^ m;
      float ar = csC[r], br = csS[r];          // ordered after writes (waitcnt)
      float nA[4], nV[4];
      #pragma unroll
      for (int k = 0; k < 4; ++k) {            // batched reads (before writes)
        int ci = c0 + 4 * k, ch = ci ^ m;
        float ac = csC[ci], bc = csS[ci];
        float a_rc = A[r * 17 + ci],  a_hc = A[rh * 17 + ci];
        float a_rh = A[r * 17 + ch],  a_hh = A[rh * 17 + ch];
        float v_rc = Vv[r * 17 + ci], v_rh = Vv[r * 17 + ch];
        nA[k] = ac * (ar * a_rc + br * a_hc) + bc * (ar * a_rh + br * a_hh);
        nV[k] = ac * v_rc + bc * v_rh;
      }
      #pragma unroll
      for (int k = 0; k < 4; ++k) {            // writes (lockstep: after reads)
        int ci = c0 + 4 * k;
        A[r * 17 + ci] = nA[k];
        Vv[r * 17 + ci] = nV[k];
      }
    }

    // ---- c_j (broadcast); Q: own column only (block 0: full + publish) ----
    float muj = A[j * 17 + j];
    if (muj < 0.f) muj = 0.f;
    c = (float)(sinvd * (double)muj);
    if (j == 0) {
      for (int e = l; e < 512; e += 64) {      // QT[jq][n] = (C*U)[n][jq]
        int jq = e >> 5, n = e & 31;
        float acc = 0.f;
        for (int k2 = 0; k2 < 16; ++k2)
          acc += CqS[n * 16 + k2] * Vv[k2 * 17 + jq];
        QTl[e] = acc;
        ws[OFF_QT + e] = acc;
      }
    } else if (l < 32) {                       // only Q[:,j] needed locally
      float acc = 0.f;
      for (int k2 = 0; k2 < 16; ++k2)
        acc += CqS[l * 16 + k2] * Vv[k2 * 17 + j];
      QTl[j * 32 + l] = acc;
    }
  }

  __syncthreads();                             // vT (wave 1) / QTl (wave 0)
  if (wv == 1) return;                         // wave 1 done

  // ---- s-projection: s[d][p] at p=l (lo) / p=64+l (hi) ----
  float s0l = 0.f, s1l = 0.f, s0h = 0.f, s1h = 0.f;
  for (int n = 0; n < NN; ++n) {
    float qv = QTl[j * 32 + n];                // broadcast
    s0l += qv * vT[(2 * n) * 101 + l];
    s1l += qv * vT[(2 * n + 1) * 101 + l];
    if (hiv) {
      s0h += qv * vT[(2 * n) * 101 + ahi];
      s1h += qv * vT[(2 * n + 1) * 101 + ahi];
    }
  }

  // ---- normalized Toeplitz: t_k = c*g_k/m0 ; b = s/m0 ----
  const float m0  = 1.0f + c * (1.0f + 1e-5f);
  const float im0 = frcp(m0);
  float gl = expf((0.01f * (float)l) * (0.01f * (float)l) * i2);
  float gh = expf((0.01f * (float)ahi) * (0.01f * (float)ahi) * i2);
  float u_lo = (l == 0) ? 1.0f : c * gl * im0;
  float u_hi = hiv ? c * gh * im0 : 0.0f;
  float v_lo = (l == 0) ? 0.0f : u_lo;          // v = (0, t1, ..)
  float v_hi = u_hi;
  float r0_lo = s0l * im0, r1_lo = s1l * im0;
  float r0_hi = hiv ? s0h * im0 : 0.0f;
  float r1_hi = hiv ? s1h * im0 : 0.0f;
  float P = 1.0f;
  float sdl = 0.f, sdh = 0.f;                   // register 1/d capture

  // ---- forward Schur: scalar lookahead, split loops ----
  float uk  = frdlane(u_lo, 0);
  float uk1 = frdlane(u_lo, 1);
  float vk1 = frdlane(v_lo, 1);
  float vk2 = frdlane(v_lo, 2);
  float r0k = frdlane(r0_lo, 0);
  float r1k = frdlane(r1_lo, 0);

  for (int k = 0; k < 60; ++k)  FWD_STEP(RD_LO)    // k+3 <= 62: lo-only reads
  for (int k = 60; k < 99; ++k) FWD_STEP(RD_MIX)   // mixed, clamped
  {                                                // k = 99 peeled
    const int k = 99;
    float iuk = frcp(uk);
    Lrow[l * 101 + k] = u_lo * iuk;
    if (hiv) Lrow[ahi * 101 + k] = u_hi * iuk;
    float dk = P * iuk * iuk;
    sdh = (ahi == k) ? dk : sdh;                   // l==99 impossible
  }

  // ---- diagonal scale: w = y / d (register sd) ----
  float x0_lo = r0_lo * sdl, x1_lo = r1_lo * sdl;
  float x0_hi = r0_hi * sdh, x1_hi = r1_hi * sdh;

  // ---- backward: L~^T x = w, residual update with prefetched row reads ----
  float Ll = Lrow[99 * 101 + l];
  float Lh = hiv ? Lrow[99 * 101 + ahi] : 0.0f;
  for (int k = 99; k >= 1; --k) {
    float nLl = Lrow[(k - 1) * 101 + l];
    float nLh = hiv ? Lrow[(k - 1) * 101 + ahi] : 0.0f;
    float xk0 = frdpos(x0_lo, x0_hi, k);
    float xk1 = frdpos(x1_lo, x1_hi, k);
    if (l < k)   { x0_lo -= xk0 * Ll; x1_lo -= xk1 * Ll; }
    if (ahi < k) { x0_hi -= xk0 * Lh; x1_hi -= xk1 * Lh; }
    Ll = nLl; Lh = nLh;
  }

  // ---- h[p][j][d] = sinv * x[p] ----
  ws[OFF_H + l * 32 + j * 2 + 0] = sinvf * x0_lo;
  ws[OFF_H + l * 32 + j * 2 + 1] = sinvf * x1_lo;
  if (hiv) {
    ws[OFF_H + ahi * 32 + j * 2 + 0] = sinvf * x0_hi;
    ws[OFF_H + ahi * 32 + j * 2 + 1] = sinvf * x1_hi;
  }
}

// =============================== K_TAIL ====================================
// 16 blocks x 256 (4 waves -> barriers REQUIRED here). float2 z/xt phases.
#define L_H   0        // 3200
#define L_QT  3200     // 512
#define L_XL  3712     // 64
#define L_BC  3776     // 99*100 = 9900
#define L_Z   13676    // 99*32  = 3168
#define L_XT  16844    // 99*64  = 6336
#define L_PS  23180    // 4*64   = 256
#define L_TOT 23436

__global__ __launch_bounds__(256) void k_tail(
    const float* __restrict__ ls_in, const float* __restrict__ beta,
    const float* __restrict__ ws, float* __restrict__ out)
{
  extern __shared__ float lds[];
  const int tid = threadIdx.x;
  const float ls = ls_in[0];
  const float i2 = -0.5f / (ls * ls);

  for (int e = tid; e < 3200; e += 256) lds[L_H + e] = ws[OFF_H + e];
  for (int e = tid; e < 512; e += 256)  lds[L_QT + e] = ws[OFF_QT + e];
  if (tid < 64) lds[L_XL + tid] = ws[OFF_XL + tid];
  for (int e = tid; e < NT * NBINS; e += 256) {
    int t = e / NBINS, p = e - t * NBINS;
    float tst = 1.0f + (float)t * (1.0f / 99.0f);
    float dd = tst - ((float)p + 0.5f) * 0.01f;
    lds[L_BC + e] = expf(dd * dd * i2);
  }
  __syncthreads();

  // z[t][jd2:jd2+2] = sum_p Bc[t][p] * h[p][jd2:jd2+2]   (float2 h reads)
  for (int dot = tid; dot < NT * 16; dot += 256) {
    int t = dot >> 4, jd2 = (dot & 15) << 1;
    float ax = 0.f, ay = 0.f;
    for (int p = 0; p < NBINS; ++p) {
      float b = lds[L_BC + t * NBINS + p];
      float2 h2 = *(const float2*)&lds[L_H + p * 32 + jd2];
      ax += b * h2.x; ay += b * h2.y;
    }
    *(float2*)&lds[L_Z + t * 32 + jd2] = make_float2(ax, ay);
  }
  __syncthreads();

  // xt[t][n][0:2] = xl[n] + trel * sum_j qt[j][n] * z[t][2j:2j+2]
  // z read is n-independent -> same-address broadcast per 32-lane group.
  for (int e = tid; e < NT * 32; e += 256) {
    int t = e >> 5, n = e & 31;
    float ax = 0.f, ay = 0.f;
    for (int jq = 0; jq < 16; ++jq) {
      float q = lds[L_QT + jq * 32 + n];
      float2 z2 = *(const float2*)&lds[L_Z + t * 32 + jq * 2];
      ax += q * z2.x; ay += q * z2.y;
    }
    float trel = (float)t * (1.0f / 99.0f);
    float2 xl = *(const float2*)&lds[L_XL + 2 * n];
    *(float2*)&lds[L_XT + t * 64 + 2 * n] =
        make_float2(xl.x + trel * ax, xl.y + trel * ay);
  }
  __syncthreads();

  // intensity: 64 pairs per block, 4-way t-split
  {
    const int pl = tid & 63, tc = tid >> 6;
    const int gp = blockIdx.x * 64 + pl;
    const int i = gp >> 5, jj = gp & 31;
    const float bsum = beta[i] + beta[jj];
    const int t0 = tc * 25, t1 = (t0 + 25 < NT) ? t0 + 25 : NT;
    float acc = 0.f;
    for (int t = t0; t < t1; ++t) {
      float2 xi = *(const float2*)&lds[L_XT + t * 64 + 2 * i];
      float2 xj = *(const float2*)&lds[L_XT + t * 64 + 2 * jj];
      float dx = xi.x - xj.x, dy = xi.y - xj.y;
      float sq = fmaxf(dx * dx + dy * dy, 1e-12f);
      acc += expf(bsum - sqrtf(sq));
    }
    lds[L_PS + tc * 64 + pl] = acc;
  }
  __syncthreads();
  if (tid < 64) {
    float s = lds[L_PS + tid] + lds[L_PS + 64 + tid]
            + lds[L_PS + 128 + tid] + lds[L_PS + 192 + tid];
    out[blockIdx.x * 64 + tid] = s * (1.0f / 99.0f);
  }
}

extern "C" void kernel_launch(void* const* d_in, const int* in_sizes, int n_in,
                              void* d_out, int out_size, void* d_ws, size_t ws_size,
                              hipStream_t stream) {
  const float* x0    = (const float*)d_in[0];
  const float* v     = (const float*)d_in[1];
  const float* beta  = (const float*)d_in[2];
  const float* sigma = (const float*)d_in[3];
  // d_in[4] = x0c: unused (B_cross row 0 is zero)
  const float* ls    = (const float*)d_in[5];
  const float* Cq    = (const float*)d_in[6];
  float* out = (float*)d_out;
  float* ws  = (float*)d_ws;

  const size_t smem1 = (size_t)(100 * 101 + 64 * 101 + 512) * sizeof(float); // ~66.7 KB
  k1_all<<<16, 128, smem1, stream>>>(x0, v, sigma, ls, Cq, ws);
  k_tail<<<16, 256, (size_t)L_TOT * sizeof(float), stream>>>(ls, beta, ws, out);
}